// Round 15
// baseline (188.498 us; speedup 1.0000x reference)
//
#include <hip/hip_runtime.h>
#include <cmath>

// ---------------------------------------------------------------------------
// GNNPooling: 3x (ChebConv -> BN(train) -> ReLU) -> mean over nodes.
// Lhat = alpha*I + beta*J  =>  y[b] = A_b @ WI + 1 * colsum(A_b @ WJ)
// Round 15 = Round 14 (best, 171us) + ONE change: L1 A-prefetch depth 2->4 kt
// (16 float4 = 64 VGPR prefetch window; wave ~230 VGPR, still <=256 so
// occupancy stays 8 waves/CU). kt>=4 loads remain inline. L2/3 already
// prefetch all kt. Everything else frozen: wave-pair per batch, 8-wave
// blocks, B in LDS once, single barrier/iter (sJw double-buffered),
// 8-slot hierarchical atomic stats, transpose-free pool.
// ---------------------------------------------------------------------------

typedef __attribute__((ext_vector_type(8))) short bf16x8;
typedef __attribute__((ext_vector_type(4))) float f32x4;

typedef __attribute__((address_space(1))) const unsigned int guint_t;
typedef __attribute__((address_space(3))) unsigned int luint_t;

constexpr int BATCH = 4096;
constexpr int DCH   = 128;
constexpr float INV_NROWS = 1.0f / 262144.0f;

// workspace offsets (in floats)
constexpr size_t OFF_G1   = 0;            // layer1 WI+WJ granules: 32768 floats
constexpr size_t OFF_G2   = 32768;        // 16384 floats
constexpr size_t OFF_G3   = 49152;        // 16384 floats
constexpr size_t OFF_RAW  = 65536;        // 3 * 8 * 256 stat slots
constexpr size_t OFF_Y    = 1180416;      // y bf16 granules: 4096*8192 ushorts

struct Coeffs { float a[5]; float b[5]; };

__device__ __forceinline__ unsigned short f2bf(float f) {
  unsigned u = __float_as_uint(f);
  u += 0x7FFFu + ((u >> 16) & 1u);        // round-to-nearest-even
  return (unsigned short)(u >> 16);
}
__device__ __forceinline__ float bf2f(unsigned short s) {
  return __uint_as_float(((unsigned)s) << 16);
}

// ---------------------------------------------------------------------------
// prep_gran: WI (= sum_k a_k W_k) and WJ (= sum_k b_k W_k) in B-fragment
// granule order, bf16. unit r = kt*512 + ct*64 + lane holds 8 values
// W[kt*32+(lane>>4)*8+i][ct*16+(lane&15)]. Also zeros raw[6144].
// ---------------------------------------------------------------------------
__global__ __launch_bounds__(256) void prep_gran(const float* __restrict__ W1,
                                                 const float* __restrict__ W2,
                                                 const float* __restrict__ W3,
                                                 float* __restrict__ ws,
                                                 float* __restrict__ raw, Coeffs co)
{
  int id = blockIdx.x * 256 + threadIdx.x;       // 0..16383
  if (id < 6144) raw[id] = 0.f;
  const float* W; int CIN, K, r; const float* cf; unsigned short* dst;
  if (id < 8192) {
    W = W1; CIN = 256; K = 5; r = id & 4095;
    cf = (id >= 4096) ? co.b : co.a;
    dst = (unsigned short*)(ws + OFF_G1) + (size_t)id * 8;
  } else if (id < 12288) {
    int e = id - 8192; W = W2; CIN = 128; K = 3; r = e & 2047;
    cf = (e >= 2048) ? co.b : co.a;
    dst = (unsigned short*)(ws + OFF_G2) + (size_t)e * 8;
  } else {
    int e = id - 12288; W = W3; CIN = 128; K = 3; r = e & 2047;
    cf = (e >= 2048) ? co.b : co.a;
    dst = (unsigned short*)(ws + OFF_G3) + (size_t)e * 8;
  }
  int kt  = r >> 9;
  int ct  = (r >> 6) & 7;
  int ln  = r & 63;
  int col = ct * 16 + (ln & 15);
  int f0  = kt * 32 + (ln >> 4) * 8;
  bf16x8 g;
#pragma unroll
  for (int i = 0; i < 8; ++i) {
    float s = 0.f;
    for (int k = 0; k < K; ++k)
      s = fmaf(cf[k], W[((size_t)k * CIN + f0 + i) * DCH + col], s);
    g[i] = (short)f2bf(s);
  }
  *reinterpret_cast<bf16x8*>(dst) = g;
}

// ---------------------------------------------------------------------------
// Fused layer: 512 threads = 8 waves = 4 wave-pairs; pair p owns one batch per
// iteration; wave half h owns rows h*32..h*32+31 (2 mt tiles of 16 rows).
// 4 iterations -> 16 batches per block. B in LDS for the whole kernel.
// ---------------------------------------------------------------------------
template <int CIN, bool FIRST>
__global__ __launch_bounds__(512) void layer_k(
    const float* __restrict__ inF,              // FIRST: x (row-major fp32)
    const unsigned short* __restrict__ inB,     // !FIRST: y bf16 granules
    unsigned short* __restrict__ yout,          // y bf16 granules
    const unsigned short* __restrict__ gran,    // WI then WJ granules (bf16)
    const float* __restrict__ rawIn,            // prev stats (8 slots) or null
    const float* __restrict__ gam, const float* __restrict__ bet,
    float* __restrict__ rawOut)                 // this layer's stats (8 slots)
{
  constexpr int NKT = CIN / 32;
  constexpr int NG  = CIN * 16;                 // bf16x8 units per matrix

  __shared__ unsigned short sB[CIN * 256];      // WI+WJ granules (CIN*512 B)
  __shared__ unsigned short slab[8][1152];      // per-wave transpose / stat alias
  __shared__ float sJw[2][4][2][DCH];           // pair J partials (double-buf)
  __shared__ float sScale[DCH];
  __shared__ float sShift[DCH];

  const int tid = threadIdx.x;
  const int wv  = tid >> 6;            // 0..7
  const int p   = wv >> 1;             // pair = batch sub-index
  const int h   = wv & 1;              // row half
  const int l   = tid & 63;
  const int lr  = l & 15;
  const int lk  = l >> 4;

  // ---- stage B once: linear global_load_lds, 8 waves x 1KB per round ----
  {
    const char* gB = reinterpret_cast<const char*>(gran);
    char* lB = reinterpret_cast<char*>(&sB[0]);
#pragma unroll
    for (int i = 0; i < (CIN * 512) / 8192; ++i) {
      const int c = i * 8 + wv;
      __builtin_amdgcn_global_load_lds(
          (guint_t*)(gB + (size_t)c * 1024 + (size_t)l * 16),
          (luint_t*)(lB + c * 1024), 16, 0, 0);
    }
  }

  // ---- A prefetch buffers (next iteration) ----
  float4 pf[FIRST ? 16 : 1];           // FIRST: kt0-3 x 2mt x 2 float4
  bf16x8 pb[FIRST ? 1 : 8];            // !FIRST: all 4 kt x 2mt granules

  // prologue prefetch for it=0 (overlaps the staging drain)
  {
    const int b0 = blockIdx.x * 16 + p;
    if constexpr (FIRST) {
      const float* ap = inF + ((size_t)b0 * 64 + h * 32 + lr) * CIN + lk * 8;
#pragma unroll
      for (int kk = 0; kk < 4; ++kk)
#pragma unroll
        for (int mt = 0; mt < 2; ++mt) {
          pf[kk * 4 + mt * 2 + 0] = *reinterpret_cast<const float4*>(ap + (size_t)mt * 16 * CIN + kk * 32);
          pf[kk * 4 + mt * 2 + 1] = *reinterpret_cast<const float4*>(ap + (size_t)mt * 16 * CIN + kk * 32 + 4);
        }
    } else {
      const bf16x8* yb0 = reinterpret_cast<const bf16x8*>(inB + (size_t)b0 * 8192);
#pragma unroll
      for (int kk = 0; kk < 4; ++kk)
#pragma unroll
        for (int mt = 0; mt < 2; ++mt)
          pb[kk * 2 + mt] = yb0[kk * 256 + (h * 2 + mt) * 64 + l];
    }
  }

  if constexpr (!FIRST) {
    if (tid < DCH) {
      float ss = 0.f, qq = 0.f;
#pragma unroll
      for (int s = 0; s < 8; ++s) {
        ss += rawIn[s * 256 + tid];
        qq += rawIn[s * 256 + 128 + tid];
      }
      float mu  = ss * INV_NROWS;
      float var = qq * INV_NROWS - mu * mu;
      float rs  = rsqrtf(var + 1e-5f);
      float sc  = gam[tid] * rs;
      sScale[tid] = sc;
      sShift[tid] = fmaf(-mu, sc, bet[tid]);
    }
  }
  __syncthreads();                              // drains staging

  const bf16x8* sBu = reinterpret_cast<const bf16x8*>(&sB[0]);

  float psum[8], psq[8];                        // per-lane stats across iters
#pragma unroll
  for (int ct = 0; ct < 8; ++ct) { psum[ct] = 0.f; psq[ct] = 0.f; }

#pragma unroll 1
  for (int it = 0; it < 4; ++it) {
    const int batch = blockIdx.x * 16 + it * 4 + p;

    f32x4 acc[8][2];                            // [ct][mt] (this half's 32 rows)
    f32x4 accJ[8];
#pragma unroll
    for (int ct = 0; ct < 8; ++ct) {
#pragma unroll
      for (int mt = 0; mt < 2; ++mt)
#pragma unroll
        for (int r = 0; r < 4; ++r) acc[ct][mt][r] = 0.f;
#pragma unroll
      for (int r = 0; r < 4; ++r) accJ[ct][r] = 0.f;
    }

#pragma unroll
    for (int kt = 0; kt < NKT; ++kt) {
      bf16x8 af[2];
      float vs[8];
#pragma unroll
      for (int i = 0; i < 8; ++i) vs[i] = 0.f;

      if constexpr (FIRST) {
        if (kt < 4) {
          // from prefetch registers
#pragma unroll
          for (int mt = 0; mt < 2; ++mt) {
            float4 u0 = pf[kt * 4 + mt * 2 + 0];
            float4 u1 = pf[kt * 4 + mt * 2 + 1];
            float v8[8] = {u0.x, u0.y, u0.z, u0.w, u1.x, u1.y, u1.z, u1.w};
#pragma unroll
            for (int i = 0; i < 8; ++i) {
              vs[i] += v8[i];
              af[mt][i] = (short)f2bf(v8[i]);
            }
          }
        } else {
          const float* ap = inF + ((size_t)batch * 64 + h * 32 + lr) * CIN + kt * 32 + lk * 8;
#pragma unroll
          for (int mt = 0; mt < 2; ++mt) {
            float4 u0 = *reinterpret_cast<const float4*>(ap + (size_t)mt * 16 * CIN);
            float4 u1 = *reinterpret_cast<const float4*>(ap + (size_t)mt * 16 * CIN + 4);
            float v8[8] = {u0.x, u0.y, u0.z, u0.w, u1.x, u1.y, u1.z, u1.w};
#pragma unroll
            for (int i = 0; i < 8; ++i) {
              vs[i] += v8[i];
              af[mt][i] = (short)f2bf(v8[i]);
            }
          }
        }
      } else {
        const int c0 = kt * 32 + lk * 8;
        const float4 s0 = *reinterpret_cast<const float4*>(&sScale[c0]);
        const float4 s1 = *reinterpret_cast<const float4*>(&sScale[c0 + 4]);
        const float4 h0 = *reinterpret_cast<const float4*>(&sShift[c0]);
        const float4 h1 = *reinterpret_cast<const float4*>(&sShift[c0 + 4]);
        const float scv[8] = {s0.x, s0.y, s0.z, s0.w, s1.x, s1.y, s1.z, s1.w};
        const float shv[8] = {h0.x, h0.y, h0.z, h0.w, h1.x, h1.y, h1.z, h1.w};
#pragma unroll
        for (int mt = 0; mt < 2; ++mt) {
          bf16x8 r16 = pb[kt * 2 + mt];
#pragma unroll
          for (int i = 0; i < 8; ++i) {
            float hv = fmaxf(fmaf(bf2f((unsigned short)r16[i]), scv[i], shv[i]), 0.f);
            vs[i] += hv;
            af[mt][i] = (short)f2bf(hv);
          }
        }
      }

      bf16x8 asum;
#pragma unroll
      for (int i = 0; i < 8; ++i) asum[i] = (short)f2bf(vs[i]);

      const bf16x8* bI = sBu + kt * 512 + l;
#pragma unroll
      for (int ct = 0; ct < 8; ++ct) {
        bf16x8 fI = bI[ct * 64];
        acc[ct][0] = __builtin_amdgcn_mfma_f32_16x16x32_bf16(af[0], fI, acc[ct][0], 0, 0, 0);
        acc[ct][1] = __builtin_amdgcn_mfma_f32_16x16x32_bf16(af[1], fI, acc[ct][1], 0, 0, 0);
      }
      const bf16x8* bJ = bI + NG;
#pragma unroll
      for (int ct = 0; ct < 8; ++ct)
        accJ[ct] = __builtin_amdgcn_mfma_f32_16x16x32_bf16(asum, bJ[ct * 64], accJ[ct], 0, 0, 0);
    }

    // ---- issue next iteration's A loads (latency hides under J + epilogue) ----
    if (it + 1 < 4) {
      const int nb = blockIdx.x * 16 + (it + 1) * 4 + p;
      if constexpr (FIRST) {
        const float* ap = inF + ((size_t)nb * 64 + h * 32 + lr) * CIN + lk * 8;
#pragma unroll
        for (int kk = 0; kk < 4; ++kk)
#pragma unroll
          for (int mt = 0; mt < 2; ++mt) {
            pf[kk * 4 + mt * 2 + 0] = *reinterpret_cast<const float4*>(ap + (size_t)mt * 16 * CIN + kk * 32);
            pf[kk * 4 + mt * 2 + 1] = *reinterpret_cast<const float4*>(ap + (size_t)mt * 16 * CIN + kk * 32 + 4);
          }
      } else {
        const bf16x8* ybn = reinterpret_cast<const bf16x8*>(inB + (size_t)nb * 8192);
#pragma unroll
        for (int kk = 0; kk < 4; ++kk)
#pragma unroll
          for (int mt = 0; mt < 2; ++mt)
            pb[kk * 2 + mt] = ybn[kk * 256 + (h * 2 + mt) * 64 + l];
      }
    }

    // J partial: colsum of this half's T over its 16 pseudo-rows
#pragma unroll
    for (int ct = 0; ct < 8; ++ct) {
      float t = (accJ[ct][0] + accJ[ct][1]) + (accJ[ct][2] + accJ[ct][3]);
      t += __shfl_xor(t, 16);
      t += __shfl_xor(t, 32);
      if (lk == 0) sJw[it & 1][p][h][ct * 16 + lr] = t;
    }
    __syncthreads();                            // single barrier per iteration
    float jv[8];
#pragma unroll
    for (int ct = 0; ct < 8; ++ct)
      jv[ct] = sJw[it & 1][p][0][ct * 16 + lr] + sJw[it & 1][p][1][ct * 16 + lr];

    // ---- epilogue: per-mt two-pass 16x72 transpose (wave-private) ----
    unsigned short* myT = &slab[wv][0];
    bf16x8* yo = reinterpret_cast<bf16x8*>(yout + (size_t)batch * 8192);
#pragma unroll
    for (int mt = 0; mt < 2; ++mt) {
      const int m = h * 2 + mt;                 // global 16-row tile index
#pragma unroll
      for (int cp = 0; cp < 2; ++cp) {
#pragma unroll
        for (int cq = 0; cq < 4; ++cq) {
          const int ct = cp * 4 + cq;
#pragma unroll
          for (int r = 0; r < 4; ++r) {
            float val = acc[ct][mt][r] + jv[ct];
            psum[ct] += val;
            psq[ct]  = fmaf(val, val, psq[ct]);
            myT[(lk * 4 + r) * 72 + cq * 16 + lr] = f2bf(val);
          }
        }
#pragma unroll
        for (int k2 = 0; k2 < 2; ++k2) {
          bf16x8 gd = *reinterpret_cast<const bf16x8*>(&myT[lr * 72 + k2 * 32 + lk * 8]);
          yo[(cp * 2 + k2) * 256 + m * 64 + l] = gd;
        }
      }
    }
  }

  // ---- stats: shuffle over lk, alias slab as float, 8-slot atomicAdd ----
#pragma unroll
  for (int ct = 0; ct < 8; ++ct) {
    psum[ct] += __shfl_xor(psum[ct], 16);
    psum[ct] += __shfl_xor(psum[ct], 32);
    psq[ct]  += __shfl_xor(psq[ct], 16);
    psq[ct]  += __shfl_xor(psq[ct], 32);
  }
  __syncthreads();                              // slab free after last epilogue
  if (lk == 0) {
    float* sRedW = reinterpret_cast<float*>(&slab[wv][0]);
#pragma unroll
    for (int ct = 0; ct < 8; ++ct) {
      sRedW[ct * 16 + lr]       = psum[ct];
      sRedW[128 + ct * 16 + lr] = psq[ct];
    }
  }
  __syncthreads();
  if (tid < 256) {
    const float* base = reinterpret_cast<const float*>(&slab[0][0]);
    float tot = 0.f;
#pragma unroll
    for (int w2 = 0; w2 < 8; ++w2) tot += base[w2 * 576 + tid];
    atomicAdd(&rawOut[(blockIdx.x & 7) * 256 + tid], tot);
  }
}

// ---------------------------------------------------------------------------
// Final BN + ReLU + mean over nodes: wave per batch, direct granule reads,
// shfl_xor row-reduce, no LDS transpose. Grid 1024 x 256.
// ---------------------------------------------------------------------------
__global__ __launch_bounds__(256) void pool_k(const unsigned short* __restrict__ y,
                                              const float* __restrict__ raw3,
                                              const float* __restrict__ gam,
                                              const float* __restrict__ bet,
                                              float* __restrict__ out)
{
  __shared__ float sScale[DCH];
  __shared__ float sShift[DCH];
  const int t = threadIdx.x;

  if (t < DCH) {
    float ss = 0.f, qq = 0.f;
#pragma unroll
    for (int s = 0; s < 8; ++s) {
      ss += raw3[s * 256 + t];
      qq += raw3[s * 256 + 128 + t];
    }
    float mu  = ss * INV_NROWS;
    float var = qq * INV_NROWS - mu * mu;
    float rr  = rsqrtf(var + 1e-5f);
    float sc  = gam[t] * rr;
    sScale[t] = sc;
    sShift[t] = fmaf(-mu, sc, bet[t]);
  }
  __syncthreads();

  const int wv = t >> 6, l = t & 63;
  const int lr = l & 15, lk = l >> 4;
  const int batch = blockIdx.x * 4 + wv;
  const bf16x8* yb = reinterpret_cast<const bf16x8*>(y + (size_t)batch * 8192);

#pragma unroll
  for (int kt = 0; kt < 4; ++kt) {
    const int c0 = kt * 32 + lk * 8;
    const float4 s0 = *reinterpret_cast<const float4*>(&sScale[c0]);
    const float4 s1 = *reinterpret_cast<const float4*>(&sScale[c0 + 4]);
    const float4 h0 = *reinterpret_cast<const float4*>(&sShift[c0]);
    const float4 h1 = *reinterpret_cast<const float4*>(&sShift[c0 + 4]);
    const float scv[8] = {s0.x, s0.y, s0.z, s0.w, s1.x, s1.y, s1.z, s1.w};
    const float shv[8] = {h0.x, h0.y, h0.z, h0.w, h1.x, h1.y, h1.z, h1.w};
    float s8[8];
#pragma unroll
    for (int i = 0; i < 8; ++i) s8[i] = 0.f;
#pragma unroll
    for (int m = 0; m < 4; ++m) {
      bf16x8 g = yb[kt * 256 + m * 64 + l];
#pragma unroll
      for (int i = 0; i < 8; ++i)
        s8[i] += fmaxf(fmaf(bf2f((unsigned short)g[i]), scv[i], shv[i]), 0.f);
    }
#pragma unroll
    for (int mask = 1; mask <= 8; mask <<= 1)
#pragma unroll
      for (int i = 0; i < 8; ++i) s8[i] += __shfl_xor(s8[i], mask, 16);
    if (lr == 0) {
      float* op = out + (size_t)batch * DCH + c0;
      *reinterpret_cast<float4*>(op) =
          make_float4(s8[0] * (1.0f / 64.0f), s8[1] * (1.0f / 64.0f),
                      s8[2] * (1.0f / 64.0f), s8[3] * (1.0f / 64.0f));
      *reinterpret_cast<float4*>(op + 4) =
          make_float4(s8[4] * (1.0f / 64.0f), s8[5] * (1.0f / 64.0f),
                      s8[6] * (1.0f / 64.0f), s8[7] * (1.0f / 64.0f));
    }
  }
}

// ---------------------------------------------------------------------------
extern "C" void kernel_launch(void* const* d_in, const int* in_sizes, int n_in,
                              void* d_out, int out_size, void* d_ws, size_t ws_size,
                              hipStream_t stream)
{
  const float* x  = (const float*)d_in[0];
  const float* W1 = (const float*)d_in[1];
  const float* W2 = (const float*)d_in[2];
  const float* W3 = (const float*)d_in[3];
  const float* g1 = (const float*)d_in[4];
  const float* b1 = (const float*)d_in[5];
  const float* g2 = (const float*)d_in[6];
  const float* b2 = (const float*)d_in[7];
  const float* g3 = (const float*)d_in[8];
  const float* b3 = (const float*)d_in[9];
  float* out = (float*)d_out;
  float* ws  = (float*)d_ws;

  Coeffs co;
  {
    double sd  = sqrt(63.0 / 4095.0);
    double av  = exp(-1.0 / sd);
    double deg = 1.0 + 63.0 * av;
    double al  = -(1.0 - av) / deg;
    double be  = -av / deg;
    double ak[5], bk[5];
    ak[0] = 1.0; bk[0] = 0.0;
    ak[1] = al;  bk[1] = be;
    for (int k = 2; k < 5; ++k) {
      ak[k] = 2.0 * al * ak[k - 1] - ak[k - 2];
      bk[k] = 2.0 * (be * ak[k - 1] + (al + 64.0 * be) * bk[k - 1]) - bk[k - 2];
    }
    for (int k = 0; k < 5; ++k) { co.a[k] = (float)ak[k]; co.b[k] = (float)bk[k]; }
  }

  const unsigned short* gr1 = (const unsigned short*)(ws + OFF_G1);
  const unsigned short* gr2 = (const unsigned short*)(ws + OFF_G2);
  const unsigned short* gr3 = (const unsigned short*)(ws + OFF_G3);
  float* raw1 = ws + OFF_RAW;
  float* raw2 = raw1 + 2048;
  float* raw3 = raw1 + 4096;
  unsigned short* yv = (unsigned short*)(ws + OFF_Y);

  prep_gran<<<64, 256, 0, stream>>>(W1, W2, W3, ws, raw1, co);

  layer_k<256, true ><<<256, 512, 0, stream>>>(x, nullptr, yv, gr1,
                                               nullptr, nullptr, nullptr, raw1);
  layer_k<128, false><<<256, 512, 0, stream>>>(nullptr, yv, yv, gr2,
                                               raw1, g1, b1, raw2);
  layer_k<128, false><<<256, 512, 0, stream>>>(nullptr, yv, yv, gr3,
                                               raw2, g2, b2, raw3);
  pool_k<<<1024, 256, 0, stream>>>(yv, raw3, g3, b3, out);

  (void)in_sizes; (void)n_in; (void)out_size; (void)ws_size;
}

// Round 16
// 170.187 us; speedup vs baseline: 1.1076x; 1.1076x over previous
//
#include <hip/hip_runtime.h>
#include <cmath>

// ---------------------------------------------------------------------------
// GNNPooling: 3x (ChebConv -> BN(train) -> ReLU) -> mean over nodes.
// Lhat = alpha*I + beta*J  =>  y[b] = A_b @ WI + 1 * colsum(A_b @ WJ)
// Round 16 = Round 14 verbatim (best, 171us). R15's 4-kt prefetch window
// exceeded the 8-wave register budget (spill signature) -> reverted to the
// proven 2-kt window. Structure: wave-pair per batch (96 acc regs), 8-wave
// 512-thr blocks, B in LDS once per block, A-prefetch across the single
// per-iteration barrier (sJw double-buffered), 8-slot hierarchical atomic
// BN stats, transpose-free wave-per-batch pool.
// ---------------------------------------------------------------------------

typedef __attribute__((ext_vector_type(8))) short bf16x8;
typedef __attribute__((ext_vector_type(4))) float f32x4;

typedef __attribute__((address_space(1))) const unsigned int guint_t;
typedef __attribute__((address_space(3))) unsigned int luint_t;

constexpr int BATCH = 4096;
constexpr int DCH   = 128;
constexpr float INV_NROWS = 1.0f / 262144.0f;

// workspace offsets (in floats)
constexpr size_t OFF_G1   = 0;            // layer1 WI+WJ granules: 32768 floats
constexpr size_t OFF_G2   = 32768;        // 16384 floats
constexpr size_t OFF_G3   = 49152;        // 16384 floats
constexpr size_t OFF_RAW  = 65536;        // 3 * 8 * 256 stat slots
constexpr size_t OFF_Y    = 1180416;      // y bf16 granules: 4096*8192 ushorts

struct Coeffs { float a[5]; float b[5]; };

__device__ __forceinline__ unsigned short f2bf(float f) {
  unsigned u = __float_as_uint(f);
  u += 0x7FFFu + ((u >> 16) & 1u);        // round-to-nearest-even
  return (unsigned short)(u >> 16);
}
__device__ __forceinline__ float bf2f(unsigned short s) {
  return __uint_as_float(((unsigned)s) << 16);
}

// ---------------------------------------------------------------------------
// prep_gran: WI (= sum_k a_k W_k) and WJ (= sum_k b_k W_k) in B-fragment
// granule order, bf16. unit r = kt*512 + ct*64 + lane holds 8 values
// W[kt*32+(lane>>4)*8+i][ct*16+(lane&15)]. Also zeros raw[6144].
// ---------------------------------------------------------------------------
__global__ __launch_bounds__(256) void prep_gran(const float* __restrict__ W1,
                                                 const float* __restrict__ W2,
                                                 const float* __restrict__ W3,
                                                 float* __restrict__ ws,
                                                 float* __restrict__ raw, Coeffs co)
{
  int id = blockIdx.x * 256 + threadIdx.x;       // 0..16383
  if (id < 6144) raw[id] = 0.f;
  const float* W; int CIN, K, r; const float* cf; unsigned short* dst;
  if (id < 8192) {
    W = W1; CIN = 256; K = 5; r = id & 4095;
    cf = (id >= 4096) ? co.b : co.a;
    dst = (unsigned short*)(ws + OFF_G1) + (size_t)id * 8;
  } else if (id < 12288) {
    int e = id - 8192; W = W2; CIN = 128; K = 3; r = e & 2047;
    cf = (e >= 2048) ? co.b : co.a;
    dst = (unsigned short*)(ws + OFF_G2) + (size_t)e * 8;
  } else {
    int e = id - 12288; W = W3; CIN = 128; K = 3; r = e & 2047;
    cf = (e >= 2048) ? co.b : co.a;
    dst = (unsigned short*)(ws + OFF_G3) + (size_t)e * 8;
  }
  int kt  = r >> 9;
  int ct  = (r >> 6) & 7;
  int ln  = r & 63;
  int col = ct * 16 + (ln & 15);
  int f0  = kt * 32 + (ln >> 4) * 8;
  bf16x8 g;
#pragma unroll
  for (int i = 0; i < 8; ++i) {
    float s = 0.f;
    for (int k = 0; k < K; ++k)
      s = fmaf(cf[k], W[((size_t)k * CIN + f0 + i) * DCH + col], s);
    g[i] = (short)f2bf(s);
  }
  *reinterpret_cast<bf16x8*>(dst) = g;
}

// ---------------------------------------------------------------------------
// Fused layer: 512 threads = 8 waves = 4 wave-pairs; pair p owns one batch per
// iteration; wave half h owns rows h*32..h*32+31 (2 mt tiles of 16 rows).
// 4 iterations -> 16 batches per block. B in LDS for the whole kernel.
// ---------------------------------------------------------------------------
template <int CIN, bool FIRST>
__global__ __launch_bounds__(512) void layer_k(
    const float* __restrict__ inF,              // FIRST: x (row-major fp32)
    const unsigned short* __restrict__ inB,     // !FIRST: y bf16 granules
    unsigned short* __restrict__ yout,          // y bf16 granules
    const unsigned short* __restrict__ gran,    // WI then WJ granules (bf16)
    const float* __restrict__ rawIn,            // prev stats (8 slots) or null
    const float* __restrict__ gam, const float* __restrict__ bet,
    float* __restrict__ rawOut)                 // this layer's stats (8 slots)
{
  constexpr int NKT = CIN / 32;
  constexpr int NG  = CIN * 16;                 // bf16x8 units per matrix

  __shared__ unsigned short sB[CIN * 256];      // WI+WJ granules (CIN*512 B)
  __shared__ unsigned short slab[8][1152];      // per-wave transpose / stat alias
  __shared__ float sJw[2][4][2][DCH];           // pair J partials (double-buf)
  __shared__ float sScale[DCH];
  __shared__ float sShift[DCH];

  const int tid = threadIdx.x;
  const int wv  = tid >> 6;            // 0..7
  const int p   = wv >> 1;             // pair = batch sub-index
  const int h   = wv & 1;              // row half
  const int l   = tid & 63;
  const int lr  = l & 15;
  const int lk  = l >> 4;

  // ---- stage B once: linear global_load_lds, 8 waves x 1KB per round ----
  {
    const char* gB = reinterpret_cast<const char*>(gran);
    char* lB = reinterpret_cast<char*>(&sB[0]);
#pragma unroll
    for (int i = 0; i < (CIN * 512) / 8192; ++i) {
      const int c = i * 8 + wv;
      __builtin_amdgcn_global_load_lds(
          (guint_t*)(gB + (size_t)c * 1024 + (size_t)l * 16),
          (luint_t*)(lB + c * 1024), 16, 0, 0);
    }
  }

  // ---- A prefetch buffers (next iteration) ----
  float4 pf[FIRST ? 8 : 1];            // FIRST: kt0-1 x 2mt x 2 float4
  bf16x8 pb[FIRST ? 1 : 8];            // !FIRST: all 4 kt x 2mt granules

  // prologue prefetch for it=0 (overlaps the staging drain)
  {
    const int b0 = blockIdx.x * 16 + p;
    if constexpr (FIRST) {
      const float* ap = inF + ((size_t)b0 * 64 + h * 32 + lr) * CIN + lk * 8;
#pragma unroll
      for (int kk = 0; kk < 2; ++kk)
#pragma unroll
        for (int mt = 0; mt < 2; ++mt) {
          pf[kk * 4 + mt * 2 + 0] = *reinterpret_cast<const float4*>(ap + (size_t)mt * 16 * CIN + kk * 32);
          pf[kk * 4 + mt * 2 + 1] = *reinterpret_cast<const float4*>(ap + (size_t)mt * 16 * CIN + kk * 32 + 4);
        }
    } else {
      const bf16x8* yb0 = reinterpret_cast<const bf16x8*>(inB + (size_t)b0 * 8192);
#pragma unroll
      for (int kk = 0; kk < 4; ++kk)
#pragma unroll
        for (int mt = 0; mt < 2; ++mt)
          pb[kk * 2 + mt] = yb0[kk * 256 + (h * 2 + mt) * 64 + l];
    }
  }

  if constexpr (!FIRST) {
    if (tid < DCH) {
      float ss = 0.f, qq = 0.f;
#pragma unroll
      for (int s = 0; s < 8; ++s) {
        ss += rawIn[s * 256 + tid];
        qq += rawIn[s * 256 + 128 + tid];
      }
      float mu  = ss * INV_NROWS;
      float var = qq * INV_NROWS - mu * mu;
      float rs  = rsqrtf(var + 1e-5f);
      float sc  = gam[tid] * rs;
      sScale[tid] = sc;
      sShift[tid] = fmaf(-mu, sc, bet[tid]);
    }
  }
  __syncthreads();                              // drains staging

  const bf16x8* sBu = reinterpret_cast<const bf16x8*>(&sB[0]);

  float psum[8], psq[8];                        // per-lane stats across iters
#pragma unroll
  for (int ct = 0; ct < 8; ++ct) { psum[ct] = 0.f; psq[ct] = 0.f; }

#pragma unroll 1
  for (int it = 0; it < 4; ++it) {
    const int batch = blockIdx.x * 16 + it * 4 + p;

    f32x4 acc[8][2];                            // [ct][mt] (this half's 32 rows)
    f32x4 accJ[8];
#pragma unroll
    for (int ct = 0; ct < 8; ++ct) {
#pragma unroll
      for (int mt = 0; mt < 2; ++mt)
#pragma unroll
        for (int r = 0; r < 4; ++r) acc[ct][mt][r] = 0.f;
#pragma unroll
      for (int r = 0; r < 4; ++r) accJ[ct][r] = 0.f;
    }

#pragma unroll
    for (int kt = 0; kt < NKT; ++kt) {
      bf16x8 af[2];
      float vs[8];
#pragma unroll
      for (int i = 0; i < 8; ++i) vs[i] = 0.f;

      if constexpr (FIRST) {
        if (kt < 2) {
          // from prefetch registers
#pragma unroll
          for (int mt = 0; mt < 2; ++mt) {
            float4 u0 = pf[kt * 4 + mt * 2 + 0];
            float4 u1 = pf[kt * 4 + mt * 2 + 1];
            float v8[8] = {u0.x, u0.y, u0.z, u0.w, u1.x, u1.y, u1.z, u1.w};
#pragma unroll
            for (int i = 0; i < 8; ++i) {
              vs[i] += v8[i];
              af[mt][i] = (short)f2bf(v8[i]);
            }
          }
        } else {
          const float* ap = inF + ((size_t)batch * 64 + h * 32 + lr) * CIN + kt * 32 + lk * 8;
#pragma unroll
          for (int mt = 0; mt < 2; ++mt) {
            float4 u0 = *reinterpret_cast<const float4*>(ap + (size_t)mt * 16 * CIN);
            float4 u1 = *reinterpret_cast<const float4*>(ap + (size_t)mt * 16 * CIN + 4);
            float v8[8] = {u0.x, u0.y, u0.z, u0.w, u1.x, u1.y, u1.z, u1.w};
#pragma unroll
            for (int i = 0; i < 8; ++i) {
              vs[i] += v8[i];
              af[mt][i] = (short)f2bf(v8[i]);
            }
          }
        }
      } else {
        const int c0 = kt * 32 + lk * 8;
        const float4 s0 = *reinterpret_cast<const float4*>(&sScale[c0]);
        const float4 s1 = *reinterpret_cast<const float4*>(&sScale[c0 + 4]);
        const float4 h0 = *reinterpret_cast<const float4*>(&sShift[c0]);
        const float4 h1 = *reinterpret_cast<const float4*>(&sShift[c0 + 4]);
        const float scv[8] = {s0.x, s0.y, s0.z, s0.w, s1.x, s1.y, s1.z, s1.w};
        const float shv[8] = {h0.x, h0.y, h0.z, h0.w, h1.x, h1.y, h1.z, h1.w};
#pragma unroll
        for (int mt = 0; mt < 2; ++mt) {
          bf16x8 r16 = pb[kt * 2 + mt];
#pragma unroll
          for (int i = 0; i < 8; ++i) {
            float hv = fmaxf(fmaf(bf2f((unsigned short)r16[i]), scv[i], shv[i]), 0.f);
            vs[i] += hv;
            af[mt][i] = (short)f2bf(hv);
          }
        }
      }

      bf16x8 asum;
#pragma unroll
      for (int i = 0; i < 8; ++i) asum[i] = (short)f2bf(vs[i]);

      const bf16x8* bI = sBu + kt * 512 + l;
#pragma unroll
      for (int ct = 0; ct < 8; ++ct) {
        bf16x8 fI = bI[ct * 64];
        acc[ct][0] = __builtin_amdgcn_mfma_f32_16x16x32_bf16(af[0], fI, acc[ct][0], 0, 0, 0);
        acc[ct][1] = __builtin_amdgcn_mfma_f32_16x16x32_bf16(af[1], fI, acc[ct][1], 0, 0, 0);
      }
      const bf16x8* bJ = bI + NG;
#pragma unroll
      for (int ct = 0; ct < 8; ++ct)
        accJ[ct] = __builtin_amdgcn_mfma_f32_16x16x32_bf16(asum, bJ[ct * 64], accJ[ct], 0, 0, 0);
    }

    // ---- issue next iteration's A loads (latency hides under J + epilogue) ----
    if (it + 1 < 4) {
      const int nb = blockIdx.x * 16 + (it + 1) * 4 + p;
      if constexpr (FIRST) {
        const float* ap = inF + ((size_t)nb * 64 + h * 32 + lr) * CIN + lk * 8;
#pragma unroll
        for (int kk = 0; kk < 2; ++kk)
#pragma unroll
          for (int mt = 0; mt < 2; ++mt) {
            pf[kk * 4 + mt * 2 + 0] = *reinterpret_cast<const float4*>(ap + (size_t)mt * 16 * CIN + kk * 32);
            pf[kk * 4 + mt * 2 + 1] = *reinterpret_cast<const float4*>(ap + (size_t)mt * 16 * CIN + kk * 32 + 4);
          }
      } else {
        const bf16x8* ybn = reinterpret_cast<const bf16x8*>(inB + (size_t)nb * 8192);
#pragma unroll
        for (int kk = 0; kk < 4; ++kk)
#pragma unroll
          for (int mt = 0; mt < 2; ++mt)
            pb[kk * 2 + mt] = ybn[kk * 256 + (h * 2 + mt) * 64 + l];
      }
    }

    // J partial: colsum of this half's T over its 16 pseudo-rows
#pragma unroll
    for (int ct = 0; ct < 8; ++ct) {
      float t = (accJ[ct][0] + accJ[ct][1]) + (accJ[ct][2] + accJ[ct][3]);
      t += __shfl_xor(t, 16);
      t += __shfl_xor(t, 32);
      if (lk == 0) sJw[it & 1][p][h][ct * 16 + lr] = t;
    }
    __syncthreads();                            // single barrier per iteration
    float jv[8];
#pragma unroll
    for (int ct = 0; ct < 8; ++ct)
      jv[ct] = sJw[it & 1][p][0][ct * 16 + lr] + sJw[it & 1][p][1][ct * 16 + lr];

    // ---- epilogue: per-mt two-pass 16x72 transpose (wave-private) ----
    unsigned short* myT = &slab[wv][0];
    bf16x8* yo = reinterpret_cast<bf16x8*>(yout + (size_t)batch * 8192);
#pragma unroll
    for (int mt = 0; mt < 2; ++mt) {
      const int m = h * 2 + mt;                 // global 16-row tile index
#pragma unroll
      for (int cp = 0; cp < 2; ++cp) {
#pragma unroll
        for (int cq = 0; cq < 4; ++cq) {
          const int ct = cp * 4 + cq;
#pragma unroll
          for (int r = 0; r < 4; ++r) {
            float val = acc[ct][mt][r] + jv[ct];
            psum[ct] += val;
            psq[ct]  = fmaf(val, val, psq[ct]);
            myT[(lk * 4 + r) * 72 + cq * 16 + lr] = f2bf(val);
          }
        }
#pragma unroll
        for (int k2 = 0; k2 < 2; ++k2) {
          bf16x8 gd = *reinterpret_cast<const bf16x8*>(&myT[lr * 72 + k2 * 32 + lk * 8]);
          yo[(cp * 2 + k2) * 256 + m * 64 + l] = gd;
        }
      }
    }
  }

  // ---- stats: shuffle over lk, alias slab as float, 8-slot atomicAdd ----
#pragma unroll
  for (int ct = 0; ct < 8; ++ct) {
    psum[ct] += __shfl_xor(psum[ct], 16);
    psum[ct] += __shfl_xor(psum[ct], 32);
    psq[ct]  += __shfl_xor(psq[ct], 16);
    psq[ct]  += __shfl_xor(psq[ct], 32);
  }
  __syncthreads();                              // slab free after last epilogue
  if (lk == 0) {
    float* sRedW = reinterpret_cast<float*>(&slab[wv][0]);
#pragma unroll
    for (int ct = 0; ct < 8; ++ct) {
      sRedW[ct * 16 + lr]       = psum[ct];
      sRedW[128 + ct * 16 + lr] = psq[ct];
    }
  }
  __syncthreads();
  if (tid < 256) {
    const float* base = reinterpret_cast<const float*>(&slab[0][0]);
    float tot = 0.f;
#pragma unroll
    for (int w2 = 0; w2 < 8; ++w2) tot += base[w2 * 576 + tid];
    atomicAdd(&rawOut[(blockIdx.x & 7) * 256 + tid], tot);
  }
}

// ---------------------------------------------------------------------------
// Final BN + ReLU + mean over nodes: wave per batch, direct granule reads,
// shfl_xor row-reduce, no LDS transpose. Grid 1024 x 256.
// ---------------------------------------------------------------------------
__global__ __launch_bounds__(256) void pool_k(const unsigned short* __restrict__ y,
                                              const float* __restrict__ raw3,
                                              const float* __restrict__ gam,
                                              const float* __restrict__ bet,
                                              float* __restrict__ out)
{
  __shared__ float sScale[DCH];
  __shared__ float sShift[DCH];
  const int t = threadIdx.x;

  if (t < DCH) {
    float ss = 0.f, qq = 0.f;
#pragma unroll
    for (int s = 0; s < 8; ++s) {
      ss += raw3[s * 256 + t];
      qq += raw3[s * 256 + 128 + t];
    }
    float mu  = ss * INV_NROWS;
    float var = qq * INV_NROWS - mu * mu;
    float rr  = rsqrtf(var + 1e-5f);
    float sc  = gam[t] * rr;
    sScale[t] = sc;
    sShift[t] = fmaf(-mu, sc, bet[t]);
  }
  __syncthreads();

  const int wv = t >> 6, l = t & 63;
  const int lr = l & 15, lk = l >> 4;
  const int batch = blockIdx.x * 4 + wv;
  const bf16x8* yb = reinterpret_cast<const bf16x8*>(y + (size_t)batch * 8192);

#pragma unroll
  for (int kt = 0; kt < 4; ++kt) {
    const int c0 = kt * 32 + lk * 8;
    const float4 s0 = *reinterpret_cast<const float4*>(&sScale[c0]);
    const float4 s1 = *reinterpret_cast<const float4*>(&sScale[c0 + 4]);
    const float4 h0 = *reinterpret_cast<const float4*>(&sShift[c0]);
    const float4 h1 = *reinterpret_cast<const float4*>(&sShift[c0 + 4]);
    const float scv[8] = {s0.x, s0.y, s0.z, s0.w, s1.x, s1.y, s1.z, s1.w};
    const float shv[8] = {h0.x, h0.y, h0.z, h0.w, h1.x, h1.y, h1.z, h1.w};
    float s8[8];
#pragma unroll
    for (int i = 0; i < 8; ++i) s8[i] = 0.f;
#pragma unroll
    for (int m = 0; m < 4; ++m) {
      bf16x8 g = yb[kt * 256 + m * 64 + l];
#pragma unroll
      for (int i = 0; i < 8; ++i)
        s8[i] += fmaxf(fmaf(bf2f((unsigned short)g[i]), scv[i], shv[i]), 0.f);
    }
#pragma unroll
    for (int mask = 1; mask <= 8; mask <<= 1)
#pragma unroll
      for (int i = 0; i < 8; ++i) s8[i] += __shfl_xor(s8[i], mask, 16);
    if (lr == 0) {
      float* op = out + (size_t)batch * DCH + c0;
      *reinterpret_cast<float4*>(op) =
          make_float4(s8[0] * (1.0f / 64.0f), s8[1] * (1.0f / 64.0f),
                      s8[2] * (1.0f / 64.0f), s8[3] * (1.0f / 64.0f));
      *reinterpret_cast<float4*>(op + 4) =
          make_float4(s8[4] * (1.0f / 64.0f), s8[5] * (1.0f / 64.0f),
                      s8[6] * (1.0f / 64.0f), s8[7] * (1.0f / 64.0f));
    }
  }
}

// ---------------------------------------------------------------------------
extern "C" void kernel_launch(void* const* d_in, const int* in_sizes, int n_in,
                              void* d_out, int out_size, void* d_ws, size_t ws_size,
                              hipStream_t stream)
{
  const float* x  = (const float*)d_in[0];
  const float* W1 = (const float*)d_in[1];
  const float* W2 = (const float*)d_in[2];
  const float* W3 = (const float*)d_in[3];
  const float* g1 = (const float*)d_in[4];
  const float* b1 = (const float*)d_in[5];
  const float* g2 = (const float*)d_in[6];
  const float* b2 = (const float*)d_in[7];
  const float* g3 = (const float*)d_in[8];
  const float* b3 = (const float*)d_in[9];
  float* out = (float*)d_out;
  float* ws  = (float*)d_ws;

  Coeffs co;
  {
    double sd  = sqrt(63.0 / 4095.0);
    double av  = exp(-1.0 / sd);
    double deg = 1.0 + 63.0 * av;
    double al  = -(1.0 - av) / deg;
    double be  = -av / deg;
    double ak[5], bk[5];
    ak[0] = 1.0; bk[0] = 0.0;
    ak[1] = al;  bk[1] = be;
    for (int k = 2; k < 5; ++k) {
      ak[k] = 2.0 * al * ak[k - 1] - ak[k - 2];
      bk[k] = 2.0 * (be * ak[k - 1] + (al + 64.0 * be) * bk[k - 1]) - bk[k - 2];
    }
    for (int k = 0; k < 5; ++k) { co.a[k] = (float)ak[k]; co.b[k] = (float)bk[k]; }
  }

  const unsigned short* gr1 = (const unsigned short*)(ws + OFF_G1);
  const unsigned short* gr2 = (const unsigned short*)(ws + OFF_G2);
  const unsigned short* gr3 = (const unsigned short*)(ws + OFF_G3);
  float* raw1 = ws + OFF_RAW;
  float* raw2 = raw1 + 2048;
  float* raw3 = raw1 + 4096;
  unsigned short* yv = (unsigned short*)(ws + OFF_Y);

  prep_gran<<<64, 256, 0, stream>>>(W1, W2, W3, ws, raw1, co);

  layer_k<256, true ><<<256, 512, 0, stream>>>(x, nullptr, yv, gr1,
                                               nullptr, nullptr, nullptr, raw1);
  layer_k<128, false><<<256, 512, 0, stream>>>(nullptr, yv, yv, gr2,
                                               raw1, g1, b1, raw2);
  layer_k<128, false><<<256, 512, 0, stream>>>(nullptr, yv, yv, gr3,
                                               raw2, g2, b2, raw3);
  pool_k<<<1024, 256, 0, stream>>>(yv, raw3, g3, b3, out);

  (void)in_sizes; (void)n_in; (void)out_size; (void)ws_size;
}